// Round 5
// baseline (141.291 us; speedup 1.0000x reference)
//
#include <hip/hip_runtime.h>
#include <hip/hip_fp16.h>

constexpr int N_NODES = 100000;
constexpr int N_EDGES = 1600000;
constexpr int D = 64;

// ---- deterministic split parameters ----
constexpr int SH2    = 6;                                  // 64 nodes / bucket
constexpr int BSZ    = 1 << SH2;                           // 64
constexpr int NB     = (N_NODES + BSZ - 1) / BSZ;          // 1563 buckets
constexpr int SPLITB = 256;                                // split tiles
constexpr int TILE   = (N_EDGES + SPLITB - 1) / SPLITB;    // 6250 edges / tile
constexpr int LINB   = 512;                                // linear blocks in fused front
constexpr int SRTCAP = 2048;                               // LDS srt capacity (mean 1024, sigma 32)

// ---- mid-tier (proven) scan parameters ----
constexpr int SCAN_CHUNK = 1024;
constexpr int NCHUNK = (N_NODES + SCAN_CHUNK - 1) / SCAN_CHUNK;   // 98

// ---------------------------------------------------------------------------
// K1 fused front: blocks [0,LINB) do Yh = fp16(X @ W^T) (16 waves/block),
// blocks [LINB,LINB+SPLITB) histogram their edge tile over NB buckets.
// ---------------------------------------------------------------------------
__global__ __launch_bounds__(1024) void lin_hist(
    const float* __restrict__ vertices,
    const float* __restrict__ weight,   // [64][64] row-major
    __half* __restrict__ Yh,
    const int* __restrict__ edges,
    int* __restrict__ H)
{
    if (blockIdx.x < LINB) {
        __shared__ float rowbuf[16][64];
        const int wid  = threadIdx.x >> 6;    // 0..15
        const int lane = threadIdx.x & 63;

        float w[64];
        #pragma unroll
        for (int f = 0; f < 64; ++f) w[f] = weight[lane * 64 + f];

        const int nodesPerIter = LINB * 16;
        for (int base = blockIdx.x * 16; base < N_NODES; base += nodesPerIter) {
            const int node = base + wid;
            float a = 0.0f;
            if (node < N_NODES) a = vertices[(size_t)node * D + lane];
            rowbuf[wid][lane] = a;
            __syncthreads();
            float acc = 0.0f;
            const float4* rb4 = reinterpret_cast<const float4*>(&rowbuf[wid][0]);
            #pragma unroll
            for (int f4 = 0; f4 < 16; ++f4) {           // ds_read_b128 broadcast
                float4 r = rb4[f4];
                acc += r.x * w[4*f4] + r.y * w[4*f4+1] + r.z * w[4*f4+2] + r.w * w[4*f4+3];
            }
            if (node < N_NODES) Yh[(size_t)node * D + lane] = __float2half(acc);
            __syncthreads();
        }
    } else {
        __shared__ int h[NB];
        const int b = blockIdx.x - LINB;
        for (int i = threadIdx.x; i < NB; i += 1024) h[i] = 0;
        __syncthreads();
        const int lo = b * TILE;
        const int hi = min(lo + TILE, N_EDGES);
        for (int e = lo + threadIdx.x; e < hi; e += 1024)
            atomicAdd(&h[edges[e] >> SH2], 1);
        __syncthreads();
        for (int i = threadIdx.x; i < NB; i += 1024)
            H[b * NB + i] = h[i];
    }
}

// ---------------------------------------------------------------------------
// K2 scanA: one block per bucket; exclusive-scan its column of H (SPLITB rows),
// leave exclusive values in place, emit column total.
// ---------------------------------------------------------------------------
__global__ __launch_bounds__(256) void s_scanA(int* __restrict__ H,
                                               int* __restrict__ colsum)
{
    const int j = blockIdx.x;
    const int t = threadIdx.x;
    int v = H[t * NB + j];
    __shared__ int s[256];
    s[t] = v; __syncthreads();
    for (int o = 1; o < 256; o <<= 1) {
        int u = (t >= o) ? s[t - o] : 0;
        __syncthreads();
        s[t] += u;
        __syncthreads();
    }
    H[t * NB + j] = s[t] - v;            // exclusive within column
    if (t == 255) colsum[j] = s[t];
}

// ---------------------------------------------------------------------------
// K3 scatter (1024 thr, 16 waves/CU): every block rebuilds the NB-wide bucket
// base scan in LDS (absorbs the old scanB dispatch; block 0 dumps bbase for
// the gather), seeds cursors with its deterministic (block,bucket) offset,
// writes packed (src<<6 | dst&63).
// ---------------------------------------------------------------------------
__global__ __launch_bounds__(1024) void s_scatter(const int* __restrict__ edges,
                                                  const int* __restrict__ H,
                                                  const int* __restrict__ colsum,
                                                  int* __restrict__ packed,
                                                  int* __restrict__ bbase)
{
    __shared__ int cur[NB];
    __shared__ int sd[1024];
    const int t = threadIdx.x;

    int v0 = (2*t     < NB) ? colsum[2*t]     : 0;
    int v1 = (2*t + 1 < NB) ? colsum[2*t + 1] : 0;
    int pair = v0 + v1;
    sd[t] = pair; __syncthreads();
    for (int o = 1; o < 1024; o <<= 1) {
        int u = (t >= o) ? sd[t - o] : 0;
        __syncthreads();
        sd[t] += u;
        __syncthreads();
    }
    int excl = sd[t] - pair;
    if (2*t < NB) {
        cur[2*t] = excl + H[blockIdx.x * NB + 2*t];
        if (blockIdx.x == 0) bbase[2*t] = excl;
    }
    if (2*t + 1 < NB) {
        cur[2*t + 1] = excl + v0 + H[blockIdx.x * NB + 2*t + 1];
        if (blockIdx.x == 0) bbase[2*t + 1] = excl + v0;
    }
    __syncthreads();

    const int lo = blockIdx.x * TILE;
    const int hi = min(lo + TILE, N_EDGES);
    for (int e = lo + t; e < hi; e += 1024) {
        int dst = edges[e];
        int src = edges[N_EDGES + e];
        int pos = atomicAdd(&cur[dst >> SH2], 1);
        packed[pos] = (src << SH2) | (dst & (BSZ - 1));
    }
}

// ---------------------------------------------------------------------------
// K4 fused CSR + gather: one block per 64-node bucket. Phase A builds the
// bucket CSR in LDS (srt list in 8KB LDS; global spill if cnt>SRTCAP).
// Phase B: proven 8x8-group gather (one wave64 dwordx4 fetches 8 fp16 rows),
// fp32 accumulate, shfl_xor combine, scale+bias, fp32 out.
// ---------------------------------------------------------------------------
__device__ __forceinline__ void addrow(float* acc, uint4 u)
{
    const __half2* h = reinterpret_cast<const __half2*>(&u);
    #pragma unroll
    for (int k = 0; k < 4; ++k) {
        float2 f = __half22float2(h[k]);
        acc[2 * k]     += f.x;
        acc[2 * k + 1] += f.y;
    }
}

__device__ __forceinline__ int waveInclScan(int v, int lane) {
    #pragma unroll
    for (int off = 1; off < 64; off <<= 1) {
        int t = __shfl_up(v, off, 64);
        if (lane >= off) v += t;
    }
    return v;
}

__global__ __launch_bounds__(256) void csr_gather(
    const int* __restrict__ packed,
    const int* __restrict__ bbase,
    const int* __restrict__ colsum,
    const __half* __restrict__ Yh,
    const float* __restrict__ bias,
    int* __restrict__ srtG,
    float* __restrict__ out)
{
    __shared__ int h[BSZ];
    __shared__ int excl[BSZ];
    __shared__ int cur[BSZ];
    __shared__ int srtL[SRTCAP];

    const int t = threadIdx.x;
    const int b = blockIdx.x;
    const int start = bbase[b];
    const int cnt   = colsum[b];

    // --- phase A: bucket-local CSR in LDS ---
    if (t < BSZ) h[t] = 0;
    __syncthreads();
    for (int i = t; i < cnt; i += 256)
        atomicAdd(&h[packed[start + i] & (BSZ - 1)], 1);
    __syncthreads();
    if (t < BSZ) {
        int v = h[t];
        int incl = waveInclScan(v, t);   // threads 0..63 are wave 0
        excl[t] = incl - v;
        cur[t]  = incl - v;
    }
    __syncthreads();
    const bool useG = (cnt > SRTCAP);
    if (!useG) {
        for (int i = t; i < cnt; i += 256) {
            int p = packed[start + i];
            int r = atomicAdd(&cur[p & (BSZ - 1)], 1);
            srtL[r] = p >> SH2;
        }
    } else {
        for (int i = t; i < cnt; i += 256) {
            int p = packed[start + i];
            int r = atomicAdd(&cur[p & (BSZ - 1)], 1);
            srtG[start + r] = p >> SH2;
        }
    }
    __syncthreads();

    // --- phase B: gather (wave processes 16 nodes sequentially) ---
    const int wid  = t >> 6;
    const int lane = t & 63;
    const int g    = lane >> 3;          // edge slot within octet
    const int sub  = lane & 7;           // 16B chunk within 128B row

    const float4 b0 = *reinterpret_cast<const float4*>(bias + sub * 8);
    const float4 b1 = *reinterpret_cast<const float4*>(bias + sub * 8 + 4);

    for (int m = 0; m < 16; ++m) {
        const int l = wid * 16 + m;
        const int node = (b << SH2) + l;
        if (node >= N_NODES) break;      // uniform across the wave

        const int off = excl[l];
        const int dc  = h[l];

        float acc[8];
        #pragma unroll
        for (int j = 0; j < 8; ++j) acc[j] = 0.0f;

        if (g == 0) {                    // self loop
            uint4 u = *reinterpret_cast<const uint4*>(Yh + (size_t)node * D + sub * 8);
            addrow(acc, u);
        }

        int e = 0;
        if (!useG) {
            for (; e + 16 <= dc; e += 16) {
                int s0 = srtL[off + e + g];
                int s1 = srtL[off + e + 8 + g];
                uint4 u0 = *reinterpret_cast<const uint4*>(Yh + (size_t)s0 * D + sub * 8);
                uint4 u1 = *reinterpret_cast<const uint4*>(Yh + (size_t)s1 * D + sub * 8);
                addrow(acc, u0);
                addrow(acc, u1);
            }
            if (e + 8 <= dc) {
                int s0 = srtL[off + e + g];
                uint4 u0 = *reinterpret_cast<const uint4*>(Yh + (size_t)s0 * D + sub * 8);
                addrow(acc, u0);
                e += 8;
            }
            if (e + g < dc) {
                int s0 = srtL[off + e + g];
                uint4 u0 = *reinterpret_cast<const uint4*>(Yh + (size_t)s0 * D + sub * 8);
                addrow(acc, u0);
            }
        } else {
            const int* srt = srtG + start;
            for (; e + 16 <= dc; e += 16) {
                int s0 = srt[off + e + g];
                int s1 = srt[off + e + 8 + g];
                uint4 u0 = *reinterpret_cast<const uint4*>(Yh + (size_t)s0 * D + sub * 8);
                uint4 u1 = *reinterpret_cast<const uint4*>(Yh + (size_t)s1 * D + sub * 8);
                addrow(acc, u0);
                addrow(acc, u1);
            }
            if (e + 8 <= dc) {
                int s0 = srt[off + e + g];
                uint4 u0 = *reinterpret_cast<const uint4*>(Yh + (size_t)s0 * D + sub * 8);
                addrow(acc, u0);
                e += 8;
            }
            if (e + g < dc) {
                int s0 = srt[off + e + g];
                uint4 u0 = *reinterpret_cast<const uint4*>(Yh + (size_t)s0 * D + sub * 8);
                addrow(acc, u0);
            }
        }

        #pragma unroll
        for (int j = 0; j < 8; ++j) {
            acc[j] += __shfl_xor(acc[j], 8, 64);
            acc[j] += __shfl_xor(acc[j], 16, 64);
            acc[j] += __shfl_xor(acc[j], 32, 64);
        }

        if (g == 0) {
            const float sc = rsqrtf((float)dc + 1.0f);
            float4 r0, r1;
            r0.x = acc[0] * sc + b0.x;  r0.y = acc[1] * sc + b0.y;
            r0.z = acc[2] * sc + b0.z;  r0.w = acc[3] * sc + b0.w;
            r1.x = acc[4] * sc + b1.x;  r1.y = acc[5] * sc + b1.y;
            r1.z = acc[6] * sc + b1.z;  r1.w = acc[7] * sc + b1.w;
            *reinterpret_cast<float4*>(out + (size_t)node * D + sub * 8)     = r0;
            *reinterpret_cast<float4*>(out + (size_t)node * D + sub * 8 + 4) = r1;
        }
    }
}

// ---------------------------------------------------------------------------
// mid tier: round-0 proven pipeline (fp32 throughout)
// ---------------------------------------------------------------------------

__global__ __launch_bounds__(256) void linear_kernel(
    const float* __restrict__ vertices,
    const float* __restrict__ weight,
    float* __restrict__ Y)
{
    __shared__ float rowbuf[4][64];
    const int wid  = threadIdx.x >> 6;
    const int lane = threadIdx.x & 63;
    float w[64];
    #pragma unroll
    for (int f = 0; f < 64; ++f) w[f] = weight[lane * 64 + f];
    const int nodesPerIter = gridDim.x * 4;
    for (int base = blockIdx.x * 4; base < N_NODES; base += nodesPerIter) {
        const int node = base + wid;
        float a = 0.0f;
        if (node < N_NODES) a = vertices[(size_t)node * D + lane];
        rowbuf[wid][lane] = a;
        __syncthreads();
        float acc = 0.0f;
        #pragma unroll
        for (int f = 0; f < 64; ++f)
            acc += rowbuf[wid][f] * w[f];
        if (node < N_NODES) Y[(size_t)node * D + lane] = acc;
        __syncthreads();
    }
}

__global__ __launch_bounds__(256) void gather_f32(
    const float* __restrict__ Y,
    const int* __restrict__ offsets,
    const int* __restrict__ deg,
    const int* __restrict__ sortedSrc,
    const float* __restrict__ bias,
    float* __restrict__ out)
{
    const int wid  = threadIdx.x >> 6;
    const int lane = threadIdx.x & 63;
    const int g    = lane >> 4;
    const int sub  = lane & 15;
    const int node = blockIdx.x * 4 + wid;
    if (node >= N_NODES) return;

    const int start = offsets[node];
    const int cnt   = deg[node];

    float4 acc;
    if (g == 0) {
        acc = *reinterpret_cast<const float4*>(Y + (size_t)node * D + (sub << 2));
    } else {
        acc.x = 0.0f; acc.y = 0.0f; acc.z = 0.0f; acc.w = 0.0f;
    }

    int e = 0;
    for (; e + 8 <= cnt; e += 8) {
        int s0 = sortedSrc[start + e + g];
        int s1 = sortedSrc[start + e + 4 + g];
        const float4 a0 = *reinterpret_cast<const float4*>(Y + (size_t)s0 * D + (sub << 2));
        const float4 a1 = *reinterpret_cast<const float4*>(Y + (size_t)s1 * D + (sub << 2));
        acc.x += a0.x; acc.y += a0.y; acc.z += a0.z; acc.w += a0.w;
        acc.x += a1.x; acc.y += a1.y; acc.z += a1.z; acc.w += a1.w;
    }
    if (e + 4 <= cnt) {
        int s0 = sortedSrc[start + e + g];
        const float4 a0 = *reinterpret_cast<const float4*>(Y + (size_t)s0 * D + (sub << 2));
        acc.x += a0.x; acc.y += a0.y; acc.z += a0.z; acc.w += a0.w;
        e += 4;
    }
    if (e + g < cnt) {
        int s0 = sortedSrc[start + e + g];
        const float4 a0 = *reinterpret_cast<const float4*>(Y + (size_t)s0 * D + (sub << 2));
        acc.x += a0.x; acc.y += a0.y; acc.z += a0.z; acc.w += a0.w;
    }

    acc.x += __shfl_xor(acc.x, 16, 64);
    acc.y += __shfl_xor(acc.y, 16, 64);
    acc.z += __shfl_xor(acc.z, 16, 64);
    acc.w += __shfl_xor(acc.w, 16, 64);
    acc.x += __shfl_xor(acc.x, 32, 64);
    acc.y += __shfl_xor(acc.y, 32, 64);
    acc.z += __shfl_xor(acc.z, 32, 64);
    acc.w += __shfl_xor(acc.w, 32, 64);

    if (lane < 16) {
        const float sc = rsqrtf((float)cnt + 1.0f);
        const float4 b4 = *reinterpret_cast<const float4*>(bias + (sub << 2));
        float4 r;
        r.x = acc.x * sc + b4.x;
        r.y = acc.y * sc + b4.y;
        r.z = acc.z * sc + b4.z;
        r.w = acc.w * sc + b4.w;
        *reinterpret_cast<float4*>(out + (size_t)node * D + (sub << 2)) = r;
    }
}

__global__ __launch_bounds__(256) void hist_kernel(const int* __restrict__ edges,
                                                   int* __restrict__ deg)
{
    int e = blockIdx.x * 256 + threadIdx.x;
    if (e < N_EDGES) atomicAdd(&deg[edges[e]], 1);
}

__global__ __launch_bounds__(256) void scan_part(const int* __restrict__ deg,
                                                 int* __restrict__ partial)
{
    int t = threadIdx.x;
    int base = blockIdx.x * SCAN_CHUNK + t * 4;
    int s = 0;
    #pragma unroll
    for (int k = 0; k < 4; ++k) { int i = base + k; if (i < N_NODES) s += deg[i]; }
    int lane = t & 63, wid = t >> 6;
    #pragma unroll
    for (int off = 32; off; off >>= 1) s += __shfl_down(s, off, 64);
    __shared__ int red[4];
    if (lane == 0) red[wid] = s;
    __syncthreads();
    if (t == 0) partial[blockIdx.x] = red[0] + red[1] + red[2] + red[3];
}

__global__ void scan_small(int* partial) {
    int lane = threadIdx.x;
    int v0 = (lane < NCHUNK) ? partial[lane] : 0;
    int v1 = (64 + lane < NCHUNK) ? partial[64 + lane] : 0;
    int i0 = waveInclScan(v0, lane);
    int tot0 = __shfl(i0, 63, 64);
    int i1 = waveInclScan(v1, lane) + tot0;
    if (lane < NCHUNK) partial[lane] = i0 - v0;
    if (64 + lane < NCHUNK) partial[64 + lane] = i1 - v1;
}

__global__ __launch_bounds__(256) void scan_final(const int* __restrict__ deg,
                                                  const int* __restrict__ partial,
                                                  int* __restrict__ offsets,
                                                  int* __restrict__ cursor)
{
    int t = threadIdx.x;
    int base = blockIdx.x * SCAN_CHUNK + t * 4;
    int d[4]; int s = 0;
    #pragma unroll
    for (int k = 0; k < 4; ++k) { int i = base + k; d[k] = (i < N_NODES) ? deg[i] : 0; s += d[k]; }
    __shared__ int sd[256];
    sd[t] = s; __syncthreads();
    #pragma unroll
    for (int off = 1; off < 256; off <<= 1) {
        int v = (t >= off) ? sd[t - off] : 0;
        __syncthreads();
        sd[t] += v;
        __syncthreads();
    }
    int excl = sd[t] - s + partial[blockIdx.x];
    #pragma unroll
    for (int k = 0; k < 4; ++k) {
        int i = base + k;
        if (i < N_NODES) { offsets[i] = excl; cursor[i] = excl; excl += d[k]; }
    }
}

__global__ __launch_bounds__(256) void scatter_idx(const int* __restrict__ edges,
                                                   int* __restrict__ cursor,
                                                   int* __restrict__ sortedSrc)
{
    int e = blockIdx.x * 256 + threadIdx.x;
    if (e >= N_EDGES) return;
    int dst = edges[e];
    int src = edges[N_EDGES + e];
    int pos = atomicAdd(&cursor[dst], 1);
    sortedSrc[pos] = src;
}

// ---------------------------------------------------------------------------
// last-resort fallback (round-1, proven)
// ---------------------------------------------------------------------------

__global__ __launch_bounds__(256) void fb_scatter(
    const float* __restrict__ vertices, const int* __restrict__ edges,
    float* __restrict__ agg, float* __restrict__ degF)
{
    long long tid = (long long)blockIdx.x * 256 + threadIdx.x;
    int lane = threadIdx.x & 63;
    long long e = tid >> 6;
    if (e >= N_EDGES) return;
    int dst = edges[e];
    int src = edges[N_EDGES + e];
    atomicAdd(&agg[(size_t)dst * D + lane], vertices[(size_t)src * D + lane]);
    if (lane == 0) atomicAdd(&degF[dst], 1.0f);
}

__global__ __launch_bounds__(256) void fb_finish(
    const float* __restrict__ vertices, const float* __restrict__ weight,
    const float* __restrict__ bias, const float* __restrict__ degF,
    float* __restrict__ out)
{
    __shared__ float rowbuf[4][64];
    const int wid  = threadIdx.x >> 6;
    const int lane = threadIdx.x & 63;
    float w[64];
    #pragma unroll
    for (int f = 0; f < 64; ++f) w[f] = weight[lane * 64 + f];
    const float b = bias[lane];
    const int nodesPerIter = gridDim.x * 4;
    for (int base = blockIdx.x * 4; base < N_NODES; base += nodesPerIter) {
        const int node = base + wid;
        float a = 0.0f;
        if (node < N_NODES) {
            const float scale = rsqrtf(degF[node] + 1.0f);
            a = (out[(size_t)node * D + lane] + vertices[(size_t)node * D + lane]) * scale;
        }
        rowbuf[wid][lane] = a;
        __syncthreads();
        float acc = b;
        #pragma unroll
        for (int f = 0; f < 64; ++f) acc += rowbuf[wid][f] * w[f];
        if (node < N_NODES) out[(size_t)node * D + lane] = acc;
        __syncthreads();
    }
}

extern "C" void kernel_launch(void* const* d_in, const int* in_sizes, int n_in,
                              void* d_out, int out_size, void* d_ws, size_t ws_size,
                              hipStream_t stream) {
    const float* vertices = (const float*)d_in[0];
    const int*   edges    = (const int*)d_in[1];
    const float* weight   = (const float*)d_in[2];
    const float* bias     = (const float*)d_in[3];
    float* out = (float*)d_out;

    const int threads = 256;
    const int edgeBlocks = (N_EDGES + threads - 1) / threads;

    // --- fast layout: Yh(fp16) | H[SPLITB*NB] | colsum | bbase | packed | srtG
    {
        __half* Yh    = (__half*)d_ws;
        int*   H      = (int*)(Yh + (size_t)N_NODES * D);
        int*   colsum = H + SPLITB * NB;
        int*   bbase  = colsum + NB;
        int*   packed = bbase + NB;
        int*   srtG   = packed + N_EDGES;
        size_t needed = (size_t)((char*)(srtG + N_EDGES) - (char*)d_ws);
        if (ws_size >= needed) {
            lin_hist<<<LINB + SPLITB, 1024, 0, stream>>>(vertices, weight, Yh, edges, H);
            s_scanA<<<NB, threads, 0, stream>>>(H, colsum);
            s_scatter<<<SPLITB, 1024, 0, stream>>>(edges, H, colsum, packed, bbase);
            csr_gather<<<NB, threads, 0, stream>>>(packed, bbase, colsum, Yh, bias, srtG, out);
            return;
        }
    }

    // --- mid layout (round-0 proven): Y | deg | offsets | cursor | partial[128] | srt
    {
        float* Y       = (float*)d_ws;
        int*   deg     = (int*)(Y + (size_t)N_NODES * D);
        int*   offs    = deg + N_NODES;
        int*   cursor  = offs + N_NODES;
        int*   partial = cursor + N_NODES;
        int*   srt     = partial + 128;
        size_t needed  = (size_t)((char*)(srt + N_EDGES) - (char*)d_ws);
        if (ws_size >= needed) {
            hipMemsetAsync(deg, 0, sizeof(int) * N_NODES, stream);
            linear_kernel<<<1024, threads, 0, stream>>>(vertices, weight, Y);
            hist_kernel<<<edgeBlocks, threads, 0, stream>>>(edges, deg);
            scan_part<<<NCHUNK, threads, 0, stream>>>(deg, partial);
            scan_small<<<1, 64, 0, stream>>>(partial);
            scan_final<<<NCHUNK, threads, 0, stream>>>(deg, partial, offs, cursor);
            scatter_idx<<<edgeBlocks, threads, 0, stream>>>(edges, cursor, srt);
            gather_f32<<<(N_NODES + 3) / 4, threads, 0, stream>>>(Y, offs, deg, srt, bias, out);
            return;
        }
    }

    // --- last resort
    {
        float* degF = (float*)d_ws;
        hipMemsetAsync(out, 0, sizeof(float) * (size_t)N_NODES * D, stream);
        hipMemsetAsync(degF, 0, sizeof(float) * N_NODES, stream);
        const long long totalScatter = (long long)N_EDGES * 64;
        fb_scatter<<<(int)((totalScatter + threads - 1) / threads), threads, 0, stream>>>(
            vertices, edges, out, degF);
        fb_finish<<<1024, threads, 0, stream>>>(vertices, weight, bias, degF, out);
    }
}

// Round 6
// 136.921 us; speedup vs baseline: 1.0319x; 1.0319x over previous
//
#include <hip/hip_runtime.h>
#include <hip/hip_fp16.h>

constexpr int N_NODES = 100000;
constexpr int N_EDGES = 1600000;
constexpr int D = 64;

// ---- bucket parameters (fast path) ----
constexpr int SH2    = 6;                                  // 64 nodes / bucket
constexpr int BSZ    = 1 << SH2;                           // 64
constexpr int NB     = (N_NODES + BSZ - 1) / BSZ;          // 1563 buckets
constexpr int SPLITB = 256;                                // hist tiles (K1)
constexpr int TILE   = (N_EDGES + SPLITB - 1) / SPLITB;    // 6250 edges / hist tile
constexpr int LINB   = 2048;                               // linear blocks in fused front
constexpr int TILE3  = 4096;                               // scatter tile (8 edges/thread @512)
constexpr int NBLK3  = (N_EDGES + TILE3 - 1) / TILE3;      // 391 scatter blocks

// ---- mid-tier (proven) scan parameters ----
constexpr int SCAN_CHUNK = 1024;
constexpr int NCHUNK = (N_NODES + SCAN_CHUNK - 1) / SCAN_CHUNK;   // 98

__device__ __forceinline__ int waveInclScan(int v, int lane) {
    #pragma unroll
    for (int off = 1; off < 64; off <<= 1) {
        int t = __shfl_up(v, off, 64);
        if (lane >= off) v += t;
    }
    return v;
}

// ---------------------------------------------------------------------------
// K1 fused front: blocks [0,LINB) do Yh = fp16(X @ W^T) (4 waves, 256 thr —
// round-4 proven shape, VGPRs uncapped), blocks [LINB,LINB+SPLITB) histogram
// their edge tile into LDS and atomicAdd the bucket TOTALS into bcnt.
// ---------------------------------------------------------------------------
__global__ __launch_bounds__(256) void lin_hist(
    const float* __restrict__ vertices,
    const float* __restrict__ weight,   // [64][64] row-major
    __half* __restrict__ Yh,
    const int* __restrict__ edges,
    int* __restrict__ bcnt)
{
    if (blockIdx.x < LINB) {
        __shared__ float rowbuf[4][64];
        const int wid  = threadIdx.x >> 6;
        const int lane = threadIdx.x & 63;

        float w[64];
        #pragma unroll
        for (int f = 0; f < 64; ++f) w[f] = weight[lane * 64 + f];

        const int nodesPerIter = LINB * 4;
        for (int base = blockIdx.x * 4; base < N_NODES; base += nodesPerIter) {
            const int node = base + wid;
            float a = 0.0f;
            if (node < N_NODES) a = vertices[(size_t)node * D + lane];
            rowbuf[wid][lane] = a;
            __syncthreads();
            float acc = 0.0f;
            #pragma unroll
            for (int f = 0; f < 64; ++f)
                acc += rowbuf[wid][f] * w[f];       // same-address broadcast
            if (node < N_NODES) Yh[(size_t)node * D + lane] = __float2half(acc);
            __syncthreads();
        }
    } else {
        __shared__ int h[NB];
        const int b = blockIdx.x - LINB;
        for (int i = threadIdx.x; i < NB; i += 256) h[i] = 0;
        __syncthreads();
        const int lo = b * TILE;
        const int hi = min(lo + TILE, N_EDGES);
        for (int e = lo + threadIdx.x; e < hi; e += 256)
            atomicAdd(&h[edges[e] >> SH2], 1);
        __syncthreads();
        for (int i = threadIdx.x; i < NB; i += 256) {
            int v = h[i];
            if (v) atomicAdd(&bcnt[i], v);
        }
    }
}

// ---------------------------------------------------------------------------
// K2: exclusive scan of bcnt[NB] -> bbase (kept for bucket_csr) and cursor
// (consumed by the reservation scatter). One block, 512 threads, 4 elems each.
// ---------------------------------------------------------------------------
__global__ __launch_bounds__(512) void scan_init(const int* __restrict__ bcnt,
                                                 int* __restrict__ bbase,
                                                 int* __restrict__ cursor)
{
    __shared__ int s[512];
    const int t = threadIdx.x;
    int v[4]; int loc = 0;
    #pragma unroll
    for (int k = 0; k < 4; ++k) {
        int i = t * 4 + k;
        v[k] = (i < NB) ? bcnt[i] : 0;
        loc += v[k];
    }
    s[t] = loc; __syncthreads();
    for (int o = 1; o < 512; o <<= 1) {
        int u = (t >= o) ? s[t - o] : 0;
        __syncthreads();
        s[t] += u;
        __syncthreads();
    }
    int excl = s[t] - loc;
    #pragma unroll
    for (int k = 0; k < 4; ++k) {
        int i = t * 4 + k;
        if (i < NB) { bbase[i] = excl; cursor[i] = excl; }
        excl += v[k];
    }
}

// ---------------------------------------------------------------------------
// K3 reservation scatter (391 blocks x 512 thr, 8 edges/thread in registers):
// LDS hist of the tile -> one global atomicAdd per (block,bucket) reserves a
// contiguous chunk -> LDS-cursor scatter of packed (src<<6 | dst&63).
// Chunk order across blocks is non-deterministic; each bucket region
// [bbase[j], bbase[j]+bcnt[j]) stays contiguous, which is all that matters.
// ---------------------------------------------------------------------------
__global__ __launch_bounds__(512) void s_scatter(const int* __restrict__ edges,
                                                 int* __restrict__ cursor,
                                                 int* __restrict__ packed)
{
    __shared__ int h[NB];
    __shared__ int base[NB];
    const int t = threadIdx.x;
    const int lo = blockIdx.x * TILE3;

    for (int i = t; i < NB; i += 512) h[i] = 0;
    __syncthreads();

    int myd[8];
    #pragma unroll
    for (int k = 0; k < 8; ++k) {
        int e = lo + k * 512 + t;
        myd[k] = (e < N_EDGES) ? edges[e] : -1;
        if (myd[k] >= 0) atomicAdd(&h[myd[k] >> SH2], 1);
    }
    __syncthreads();

    for (int j = t; j < NB; j += 512) {
        int c = h[j];
        base[j] = c ? atomicAdd(&cursor[j], c) : 0;
        h[j] = 0;                       // reuse as local cursor
    }
    __syncthreads();

    #pragma unroll
    for (int k = 0; k < 8; ++k) {
        if (myd[k] >= 0) {
            int e = lo + k * 512 + t;
            int src = edges[N_EDGES + e];
            int j = myd[k] >> SH2;
            int r = atomicAdd(&h[j], 1);
            packed[base[j] + r] = (src << SH2) | (myd[k] & (BSZ - 1));
        }
    }
}

// ---------------------------------------------------------------------------
// K4 bucket_csr: one block per 64-node bucket (1563 blocks). LDS hist of the
// 64 local nodes + wave scan -> exact CSR offsets/deg; scatter srcs into the
// bucket's contiguous srt span.
// ---------------------------------------------------------------------------
__global__ __launch_bounds__(256) void bucket_csr(const int* __restrict__ packed,
                                                  const int* __restrict__ bbase,
                                                  const int* __restrict__ bcnt,
                                                  int* __restrict__ offsets,
                                                  int* __restrict__ deg,
                                                  int* __restrict__ srt)
{
    __shared__ int h2[BSZ];
    __shared__ int cur2[BSZ];
    const int b = blockIdx.x;
    const int t = threadIdx.x;
    const int start = bbase[b];
    const int cnt   = bcnt[b];

    if (t < BSZ) h2[t] = 0;
    __syncthreads();
    for (int i = t; i < cnt; i += 256)
        atomicAdd(&h2[packed[start + i] & (BSZ - 1)], 1);
    __syncthreads();
    if (t < BSZ) {                       // threads 0..63 = wave 0
        int v = h2[t];
        int incl = waveInclScan(v, t);
        int excl = incl - v;
        int node = (b << SH2) + t;
        if (node < N_NODES) { offsets[node] = start + excl; deg[node] = v; }
        cur2[t] = excl;
    }
    __syncthreads();
    for (int i = t; i < cnt; i += 256) {
        int p = packed[start + i];
        int r = atomicAdd(&cur2[p & (BSZ - 1)], 1);
        srt[start + r] = p >> SH2;
    }
}

// ---------------------------------------------------------------------------
// K5 gather (round-4 proven, byte-for-byte): one wave per node, 8x8-lane
// groups; one wave64 dwordx4 fetches 8 fp16 rows; fp32 accumulate;
// shfl_xor(8,16,32) combine; scale+bias; fp32 out.
// ---------------------------------------------------------------------------
__device__ __forceinline__ void addrow(float* acc, uint4 u)
{
    const __half2* h = reinterpret_cast<const __half2*>(&u);
    #pragma unroll
    for (int k = 0; k < 4; ++k) {
        float2 f = __half22float2(h[k]);
        acc[2 * k]     += f.x;
        acc[2 * k + 1] += f.y;
    }
}

__global__ __launch_bounds__(256) void gather_h(
    const __half* __restrict__ Yh,
    const int* __restrict__ offsets,
    const int* __restrict__ deg,
    const int* __restrict__ srt,
    const float* __restrict__ bias,
    float* __restrict__ out)
{
    const int wid  = threadIdx.x >> 6;
    const int lane = threadIdx.x & 63;
    const int g    = lane >> 3;          // edge slot within octet
    const int sub  = lane & 7;           // 16B chunk within 128B row
    const int node = blockIdx.x * 4 + wid;
    if (node >= N_NODES) return;

    const int start = offsets[node];
    const int cnt   = deg[node];

    float acc[8];
    #pragma unroll
    for (int j = 0; j < 8; ++j) acc[j] = 0.0f;

    if (g == 0) {        // self loop
        uint4 u = *reinterpret_cast<const uint4*>(Yh + (size_t)node * D + sub * 8);
        addrow(acc, u);
    }

    int e = 0;
    for (; e + 16 <= cnt; e += 16) {
        int s0 = srt[start + e + g];
        int s1 = srt[start + e + 8 + g];
        uint4 u0 = *reinterpret_cast<const uint4*>(Yh + (size_t)s0 * D + sub * 8);
        uint4 u1 = *reinterpret_cast<const uint4*>(Yh + (size_t)s1 * D + sub * 8);
        addrow(acc, u0);
        addrow(acc, u1);
    }
    if (e + 8 <= cnt) {
        int s0 = srt[start + e + g];
        uint4 u0 = *reinterpret_cast<const uint4*>(Yh + (size_t)s0 * D + sub * 8);
        addrow(acc, u0);
        e += 8;
    }
    if (e + g < cnt) {
        int s0 = srt[start + e + g];
        uint4 u0 = *reinterpret_cast<const uint4*>(Yh + (size_t)s0 * D + sub * 8);
        addrow(acc, u0);
    }

    #pragma unroll
    for (int j = 0; j < 8; ++j) {
        acc[j] += __shfl_xor(acc[j], 8, 64);
        acc[j] += __shfl_xor(acc[j], 16, 64);
        acc[j] += __shfl_xor(acc[j], 32, 64);
    }

    if (g == 0) {
        const float sc = rsqrtf((float)cnt + 1.0f);
        const float4 b0 = *reinterpret_cast<const float4*>(bias + sub * 8);
        const float4 b1 = *reinterpret_cast<const float4*>(bias + sub * 8 + 4);
        float4 r0, r1;
        r0.x = acc[0] * sc + b0.x;  r0.y = acc[1] * sc + b0.y;
        r0.z = acc[2] * sc + b0.z;  r0.w = acc[3] * sc + b0.w;
        r1.x = acc[4] * sc + b1.x;  r1.y = acc[5] * sc + b1.y;
        r1.z = acc[6] * sc + b1.z;  r1.w = acc[7] * sc + b1.w;
        *reinterpret_cast<float4*>(out + (size_t)node * D + sub * 8)     = r0;
        *reinterpret_cast<float4*>(out + (size_t)node * D + sub * 8 + 4) = r1;
    }
}

// ---------------------------------------------------------------------------
// mid tier: round-0 proven pipeline (fp32 throughout)
// ---------------------------------------------------------------------------

__global__ __launch_bounds__(256) void linear_kernel(
    const float* __restrict__ vertices,
    const float* __restrict__ weight,
    float* __restrict__ Y)
{
    __shared__ float rowbuf[4][64];
    const int wid  = threadIdx.x >> 6;
    const int lane = threadIdx.x & 63;
    float w[64];
    #pragma unroll
    for (int f = 0; f < 64; ++f) w[f] = weight[lane * 64 + f];
    const int nodesPerIter = gridDim.x * 4;
    for (int base = blockIdx.x * 4; base < N_NODES; base += nodesPerIter) {
        const int node = base + wid;
        float a = 0.0f;
        if (node < N_NODES) a = vertices[(size_t)node * D + lane];
        rowbuf[wid][lane] = a;
        __syncthreads();
        float acc = 0.0f;
        #pragma unroll
        for (int f = 0; f < 64; ++f)
            acc += rowbuf[wid][f] * w[f];
        if (node < N_NODES) Y[(size_t)node * D + lane] = acc;
        __syncthreads();
    }
}

__global__ __launch_bounds__(256) void gather_f32(
    const float* __restrict__ Y,
    const int* __restrict__ offsets,
    const int* __restrict__ deg,
    const int* __restrict__ sortedSrc,
    const float* __restrict__ bias,
    float* __restrict__ out)
{
    const int wid  = threadIdx.x >> 6;
    const int lane = threadIdx.x & 63;
    const int g    = lane >> 4;
    const int sub  = lane & 15;
    const int node = blockIdx.x * 4 + wid;
    if (node >= N_NODES) return;

    const int start = offsets[node];
    const int cnt   = deg[node];

    float4 acc;
    if (g == 0) {
        acc = *reinterpret_cast<const float4*>(Y + (size_t)node * D + (sub << 2));
    } else {
        acc.x = 0.0f; acc.y = 0.0f; acc.z = 0.0f; acc.w = 0.0f;
    }

    int e = 0;
    for (; e + 8 <= cnt; e += 8) {
        int s0 = sortedSrc[start + e + g];
        int s1 = sortedSrc[start + e + 4 + g];
        const float4 a0 = *reinterpret_cast<const float4*>(Y + (size_t)s0 * D + (sub << 2));
        const float4 a1 = *reinterpret_cast<const float4*>(Y + (size_t)s1 * D + (sub << 2));
        acc.x += a0.x; acc.y += a0.y; acc.z += a0.z; acc.w += a0.w;
        acc.x += a1.x; acc.y += a1.y; acc.z += a1.z; acc.w += a1.w;
    }
    if (e + 4 <= cnt) {
        int s0 = sortedSrc[start + e + g];
        const float4 a0 = *reinterpret_cast<const float4*>(Y + (size_t)s0 * D + (sub << 2));
        acc.x += a0.x; acc.y += a0.y; acc.z += a0.z; acc.w += a0.w;
        e += 4;
    }
    if (e + g < cnt) {
        int s0 = sortedSrc[start + e + g];
        const float4 a0 = *reinterpret_cast<const float4*>(Y + (size_t)s0 * D + (sub << 2));
        acc.x += a0.x; acc.y += a0.y; acc.z += a0.z; acc.w += a0.w;
    }

    acc.x += __shfl_xor(acc.x, 16, 64);
    acc.y += __shfl_xor(acc.y, 16, 64);
    acc.z += __shfl_xor(acc.z, 16, 64);
    acc.w += __shfl_xor(acc.w, 16, 64);
    acc.x += __shfl_xor(acc.x, 32, 64);
    acc.y += __shfl_xor(acc.y, 32, 64);
    acc.z += __shfl_xor(acc.z, 32, 64);
    acc.w += __shfl_xor(acc.w, 32, 64);

    if (lane < 16) {
        const float sc = rsqrtf((float)cnt + 1.0f);
        const float4 b4 = *reinterpret_cast<const float4*>(bias + (sub << 2));
        float4 r;
        r.x = acc.x * sc + b4.x;
        r.y = acc.y * sc + b4.y;
        r.z = acc.z * sc + b4.z;
        r.w = acc.w * sc + b4.w;
        *reinterpret_cast<float4*>(out + (size_t)node * D + (sub << 2)) = r;
    }
}

__global__ __launch_bounds__(256) void hist_kernel(const int* __restrict__ edges,
                                                   int* __restrict__ deg)
{
    int e = blockIdx.x * 256 + threadIdx.x;
    if (e < N_EDGES) atomicAdd(&deg[edges[e]], 1);
}

__global__ __launch_bounds__(256) void scan_part(const int* __restrict__ deg,
                                                 int* __restrict__ partial)
{
    int t = threadIdx.x;
    int base = blockIdx.x * SCAN_CHUNK + t * 4;
    int s = 0;
    #pragma unroll
    for (int k = 0; k < 4; ++k) { int i = base + k; if (i < N_NODES) s += deg[i]; }
    int lane = t & 63, wid = t >> 6;
    #pragma unroll
    for (int off = 32; off; off >>= 1) s += __shfl_down(s, off, 64);
    __shared__ int red[4];
    if (lane == 0) red[wid] = s;
    __syncthreads();
    if (t == 0) partial[blockIdx.x] = red[0] + red[1] + red[2] + red[3];
}

__global__ void scan_small(int* partial) {
    int lane = threadIdx.x;
    int v0 = (lane < NCHUNK) ? partial[lane] : 0;
    int v1 = (64 + lane < NCHUNK) ? partial[64 + lane] : 0;
    int i0 = waveInclScan(v0, lane);
    int tot0 = __shfl(i0, 63, 64);
    int i1 = waveInclScan(v1, lane) + tot0;
    if (lane < NCHUNK) partial[lane] = i0 - v0;
    if (64 + lane < NCHUNK) partial[64 + lane] = i1 - v1;
}

__global__ __launch_bounds__(256) void scan_final(const int* __restrict__ deg,
                                                  const int* __restrict__ partial,
                                                  int* __restrict__ offsets,
                                                  int* __restrict__ cursor)
{
    int t = threadIdx.x;
    int base = blockIdx.x * SCAN_CHUNK + t * 4;
    int d[4]; int s = 0;
    #pragma unroll
    for (int k = 0; k < 4; ++k) { int i = base + k; d[k] = (i < N_NODES) ? deg[i] : 0; s += d[k]; }
    __shared__ int sd[256];
    sd[t] = s; __syncthreads();
    #pragma unroll
    for (int off = 1; off < 256; off <<= 1) {
        int v = (t >= off) ? sd[t - off] : 0;
        __syncthreads();
        sd[t] += v;
        __syncthreads();
    }
    int excl = sd[t] - s + partial[blockIdx.x];
    #pragma unroll
    for (int k = 0; k < 4; ++k) {
        int i = base + k;
        if (i < N_NODES) { offsets[i] = excl; cursor[i] = excl; excl += d[k]; }
    }
}

__global__ __launch_bounds__(256) void scatter_idx(const int* __restrict__ edges,
                                                   int* __restrict__ cursor,
                                                   int* __restrict__ sortedSrc)
{
    int e = blockIdx.x * 256 + threadIdx.x;
    if (e >= N_EDGES) return;
    int dst = edges[e];
    int src = edges[N_EDGES + e];
    int pos = atomicAdd(&cursor[dst], 1);
    sortedSrc[pos] = src;
}

// ---------------------------------------------------------------------------
// last-resort fallback (round-1, proven)
// ---------------------------------------------------------------------------

__global__ __launch_bounds__(256) void fb_scatter(
    const float* __restrict__ vertices, const int* __restrict__ edges,
    float* __restrict__ agg, float* __restrict__ degF)
{
    long long tid = (long long)blockIdx.x * 256 + threadIdx.x;
    int lane = threadIdx.x & 63;
    long long e = tid >> 6;
    if (e >= N_EDGES) return;
    int dst = edges[e];
    int src = edges[N_EDGES + e];
    atomicAdd(&agg[(size_t)dst * D + lane], vertices[(size_t)src * D + lane]);
    if (lane == 0) atomicAdd(&degF[dst], 1.0f);
}

__global__ __launch_bounds__(256) void fb_finish(
    const float* __restrict__ vertices, const float* __restrict__ weight,
    const float* __restrict__ bias, const float* __restrict__ degF,
    float* __restrict__ out)
{
    __shared__ float rowbuf[4][64];
    const int wid  = threadIdx.x >> 6;
    const int lane = threadIdx.x & 63;
    float w[64];
    #pragma unroll
    for (int f = 0; f < 64; ++f) w[f] = weight[lane * 64 + f];
    const float b = bias[lane];
    const int nodesPerIter = gridDim.x * 4;
    for (int base = blockIdx.x * 4; base < N_NODES; base += nodesPerIter) {
        const int node = base + wid;
        float a = 0.0f;
        if (node < N_NODES) {
            const float scale = rsqrtf(degF[node] + 1.0f);
            a = (out[(size_t)node * D + lane] + vertices[(size_t)node * D + lane]) * scale;
        }
        rowbuf[wid][lane] = a;
        __syncthreads();
        float acc = b;
        #pragma unroll
        for (int f = 0; f < 64; ++f) acc += rowbuf[wid][f] * w[f];
        if (node < N_NODES) out[(size_t)node * D + lane] = acc;
        __syncthreads();
    }
}

extern "C" void kernel_launch(void* const* d_in, const int* in_sizes, int n_in,
                              void* d_out, int out_size, void* d_ws, size_t ws_size,
                              hipStream_t stream) {
    const float* vertices = (const float*)d_in[0];
    const int*   edges    = (const int*)d_in[1];
    const float* weight   = (const float*)d_in[2];
    const float* bias     = (const float*)d_in[3];
    float* out = (float*)d_out;

    const int threads = 256;
    const int edgeBlocks = (N_EDGES + threads - 1) / threads;

    // --- fast layout: Yh(fp16) | bcnt | bbase | cursor | offs | deg | packed | srt
    {
        __half* Yh    = (__half*)d_ws;
        int*   bcnt   = (int*)(Yh + (size_t)N_NODES * D);
        int*   bbase  = bcnt + NB;
        int*   cursor = bbase + NB;
        int*   offs   = cursor + NB;
        int*   deg    = offs + N_NODES;
        int*   packed = deg + N_NODES;
        int*   srt    = packed + N_EDGES;
        size_t needed = (size_t)((char*)(srt + N_EDGES) - (char*)d_ws);
        if (ws_size >= needed) {
            hipMemsetAsync(bcnt, 0, sizeof(int) * NB, stream);
            lin_hist<<<LINB + SPLITB, threads, 0, stream>>>(vertices, weight, Yh, edges, bcnt);
            scan_init<<<1, 512, 0, stream>>>(bcnt, bbase, cursor);
            s_scatter<<<NBLK3, 512, 0, stream>>>(edges, cursor, packed);
            bucket_csr<<<NB, threads, 0, stream>>>(packed, bbase, bcnt, offs, deg, srt);
            gather_h<<<(N_NODES + 3) / 4, threads, 0, stream>>>(Yh, offs, deg, srt, bias, out);
            return;
        }
    }

    // --- mid layout (round-0 proven): Y | deg | offsets | cursor | partial[128] | srt
    {
        float* Y       = (float*)d_ws;
        int*   deg     = (int*)(Y + (size_t)N_NODES * D);
        int*   offs    = deg + N_NODES;
        int*   cursor  = offs + N_NODES;
        int*   partial = cursor + N_NODES;
        int*   srt     = partial + 128;
        size_t needed  = (size_t)((char*)(srt + N_EDGES) - (char*)d_ws);
        if (ws_size >= needed) {
            hipMemsetAsync(deg, 0, sizeof(int) * N_NODES, stream);
            linear_kernel<<<1024, threads, 0, stream>>>(vertices, weight, Y);
            hist_kernel<<<edgeBlocks, threads, 0, stream>>>(edges, deg);
            scan_part<<<NCHUNK, threads, 0, stream>>>(deg, partial);
            scan_small<<<1, 64, 0, stream>>>(partial);
            scan_final<<<NCHUNK, threads, 0, stream>>>(deg, partial, offs, cursor);
            scatter_idx<<<edgeBlocks, threads, 0, stream>>>(edges, cursor, srt);
            gather_f32<<<(N_NODES + 3) / 4, threads, 0, stream>>>(Y, offs, deg, srt, bias, out);
            return;
        }
    }

    // --- last resort
    {
        float* degF = (float*)d_ws;
        hipMemsetAsync(out, 0, sizeof(float) * (size_t)N_NODES * D, stream);
        hipMemsetAsync(degF, 0, sizeof(float) * N_NODES, stream);
        const long long totalScatter = (long long)N_EDGES * 64;
        fb_scatter<<<(int)((totalScatter + threads - 1) / threads), threads, 0, stream>>>(
            vertices, edges, out, degF);
        fb_finish<<<1024, threads, 0, stream>>>(vertices, weight, bias, degF, out);
    }
}

// Round 7
// 118.834 us; speedup vs baseline: 1.1890x; 1.1522x over previous
//
#include <hip/hip_runtime.h>
#include <hip/hip_fp16.h>

constexpr int N_NODES = 100000;
constexpr int N_EDGES = 1600000;
constexpr int D = 64;

// ---- coarse bucket parameters (fast path) ----
constexpr int SHC    = 9;                                  // 512 nodes / coarse bucket
constexpr int BSZC   = 1 << SHC;                           // 512
constexpr int NBC    = (N_NODES + BSZC - 1) / BSZC;        // 196 coarse buckets
constexpr int SPLITB = 256;                                // hist tiles (K1)
constexpr int TILE   = (N_EDGES + SPLITB - 1) / SPLITB;    // 6250 edges / hist tile
constexpr int LINB   = 2048;                               // linear blocks in fused front
constexpr int TILE2  = 8192;                               // scatter tile (8 e/thr @1024)
constexpr int NBLK2  = (N_EDGES + TILE2 - 1) / TILE2;      // 196 scatter blocks

// ---- mid-tier (proven) scan parameters ----
constexpr int SCAN_CHUNK = 1024;
constexpr int NCHUNK = (N_NODES + SCAN_CHUNK - 1) / SCAN_CHUNK;   // 98

__device__ __forceinline__ int waveInclScan(int v, int lane) {
    #pragma unroll
    for (int off = 1; off < 64; off <<= 1) {
        int t = __shfl_up(v, off, 64);
        if (lane >= off) v += t;
    }
    return v;
}

// ---------------------------------------------------------------------------
// K1 fused front: blocks [0,LINB) do Yh = fp16(X @ W^T) (4 waves, 256 thr —
// round-4 proven shape, VGPRs uncapped), blocks [LINB,LINB+SPLITB) histogram
// their edge tile into LDS (196 coarse counters) and add totals to bcntC.
// ---------------------------------------------------------------------------
__global__ __launch_bounds__(256) void lin_hist(
    const float* __restrict__ vertices,
    const float* __restrict__ weight,   // [64][64] row-major
    __half* __restrict__ Yh,
    const int* __restrict__ edges,
    int* __restrict__ bcntC)
{
    if (blockIdx.x < LINB) {
        __shared__ float rowbuf[4][64];
        const int wid  = threadIdx.x >> 6;
        const int lane = threadIdx.x & 63;

        float w[64];
        #pragma unroll
        for (int f = 0; f < 64; ++f) w[f] = weight[lane * 64 + f];

        const int nodesPerIter = LINB * 4;
        for (int base = blockIdx.x * 4; base < N_NODES; base += nodesPerIter) {
            const int node = base + wid;
            float a = 0.0f;
            if (node < N_NODES) a = vertices[(size_t)node * D + lane];
            rowbuf[wid][lane] = a;
            __syncthreads();
            float acc = 0.0f;
            #pragma unroll
            for (int f = 0; f < 64; ++f)
                acc += rowbuf[wid][f] * w[f];       // same-address broadcast
            if (node < N_NODES) Yh[(size_t)node * D + lane] = __float2half(acc);
            __syncthreads();
        }
    } else {
        __shared__ int h[NBC];
        const int b = blockIdx.x - LINB;
        if (threadIdx.x < NBC) h[threadIdx.x] = 0;
        __syncthreads();
        const int lo = b * TILE;
        const int hi = min(lo + TILE, N_EDGES);
        for (int e = lo + threadIdx.x; e < hi; e += 256)
            atomicAdd(&h[edges[e] >> SHC], 1);
        __syncthreads();
        if (threadIdx.x < NBC) {
            int v = h[threadIdx.x];
            if (v) atomicAdd(&bcntC[threadIdx.x], v);
        }
    }
}

// ---------------------------------------------------------------------------
// K2 reservation scatter (196 blocks x 1024 thr, 8 edges/thread in regs).
// Prologue: scan bcntC[196] in LDS -> baseC (block 0 publishes bbaseC).
// LDS hist of the tile -> one global atomicAdd per (block,bucket) reserves a
// ~42-edge (167B) contiguous chunk -> full-line writebacks. packed =
// (src<<9 | dst&511).
// ---------------------------------------------------------------------------
__global__ __launch_bounds__(1024) void s_scatter(const int* __restrict__ edges,
                                                  const int* __restrict__ bcntC,
                                                  int* __restrict__ cursorDelta,
                                                  int* __restrict__ bbaseC,
                                                  int* __restrict__ packed)
{
    __shared__ int s[256];
    __shared__ int baseC[NBC];
    __shared__ int h[NBC];
    __shared__ int chunk[NBC];
    const int t = threadIdx.x;

    int v = 0;
    if (t < 256) { v = (t < NBC) ? bcntC[t] : 0; s[t] = v; }
    __syncthreads();
    for (int o = 1; o < 256; o <<= 1) {
        int u = (t < 256 && t >= o) ? s[t - o] : 0;
        __syncthreads();
        if (t < 256) s[t] += u;
        __syncthreads();
    }
    if (t < NBC) {
        int e = s[t] - v;
        baseC[t] = e;
        h[t] = 0;
        if (blockIdx.x == 0) bbaseC[t] = e;
    }
    __syncthreads();

    const int lo = blockIdx.x * TILE2;
    int myd[8];
    #pragma unroll
    for (int k = 0; k < 8; ++k) {
        int e = lo + k * 1024 + t;
        myd[k] = (e < N_EDGES) ? edges[e] : -1;
        if (myd[k] >= 0) atomicAdd(&h[myd[k] >> SHC], 1);
    }
    __syncthreads();

    if (t < NBC) {
        int c = h[t];
        chunk[t] = c ? (baseC[t] + atomicAdd(&cursorDelta[t], c)) : 0;
        h[t] = 0;                        // reuse as local cursor
    }
    __syncthreads();

    #pragma unroll
    for (int k = 0; k < 8; ++k) {
        if (myd[k] >= 0) {
            int e = lo + k * 1024 + t;
            int src = edges[N_EDGES + e];
            int j = myd[k] >> SHC;
            int r = atomicAdd(&h[j], 1);
            packed[chunk[j] + r] = (src << SHC) | (myd[k] & (BSZC - 1));
        }
    }
}

// ---------------------------------------------------------------------------
// K3 csr512: one block per coarse region (196 x 1024 thr). LDS hist of 512
// local nodes + scan -> exact CSR offsets/deg; scatter srcs into the region's
// contiguous srt span (single writer -> full-line writebacks).
// ---------------------------------------------------------------------------
__global__ __launch_bounds__(1024) void csr512(const int* __restrict__ packed,
                                               const int* __restrict__ bbaseC,
                                               const int* __restrict__ bcntC,
                                               int* __restrict__ offsets,
                                               int* __restrict__ deg,
                                               int* __restrict__ srt)
{
    __shared__ int h2[BSZC];
    __shared__ int cur2[BSZC];
    __shared__ int s[BSZC];
    const int b = blockIdx.x;
    const int t = threadIdx.x;
    const int start = bbaseC[b];
    const int cnt   = bcntC[b];

    if (t < BSZC) h2[t] = 0;
    __syncthreads();
    for (int i = t; i < cnt; i += 1024)
        atomicAdd(&h2[packed[start + i] & (BSZC - 1)], 1);
    __syncthreads();

    if (t < BSZC) s[t] = h2[t];
    __syncthreads();
    for (int o = 1; o < BSZC; o <<= 1) {
        int u = (t < BSZC && t >= o) ? s[t - o] : 0;
        __syncthreads();
        if (t < BSZC) s[t] += u;
        __syncthreads();
    }
    if (t < BSZC) {
        int excl = s[t] - h2[t];
        int node = (b << SHC) + t;
        if (node < N_NODES) { offsets[node] = start + excl; deg[node] = h2[t]; }
        cur2[t] = excl;
    }
    __syncthreads();
    for (int i = t; i < cnt; i += 1024) {
        int p = packed[start + i];
        int r = atomicAdd(&cur2[p & (BSZC - 1)], 1);
        srt[start + r] = p >> SHC;
    }
}

// ---------------------------------------------------------------------------
// K4 gather (round-4 proven, byte-for-byte): one wave per node, 8x8-lane
// groups; one wave64 dwordx4 fetches 8 fp16 rows; fp32 accumulate;
// shfl_xor(8,16,32) combine; scale+bias; fp32 out.
// ---------------------------------------------------------------------------
__device__ __forceinline__ void addrow(float* acc, uint4 u)
{
    const __half2* h = reinterpret_cast<const __half2*>(&u);
    #pragma unroll
    for (int k = 0; k < 4; ++k) {
        float2 f = __half22float2(h[k]);
        acc[2 * k]     += f.x;
        acc[2 * k + 1] += f.y;
    }
}

__global__ __launch_bounds__(256) void gather_h(
    const __half* __restrict__ Yh,
    const int* __restrict__ offsets,
    const int* __restrict__ deg,
    const int* __restrict__ srt,
    const float* __restrict__ bias,
    float* __restrict__ out)
{
    const int wid  = threadIdx.x >> 6;
    const int lane = threadIdx.x & 63;
    const int g    = lane >> 3;          // edge slot within octet
    const int sub  = lane & 7;           // 16B chunk within 128B row
    const int node = blockIdx.x * 4 + wid;
    if (node >= N_NODES) return;

    const int start = offsets[node];
    const int cnt   = deg[node];

    float acc[8];
    #pragma unroll
    for (int j = 0; j < 8; ++j) acc[j] = 0.0f;

    if (g == 0) {        // self loop
        uint4 u = *reinterpret_cast<const uint4*>(Yh + (size_t)node * D + sub * 8);
        addrow(acc, u);
    }

    int e = 0;
    for (; e + 16 <= cnt; e += 16) {
        int s0 = srt[start + e + g];
        int s1 = srt[start + e + 8 + g];
        uint4 u0 = *reinterpret_cast<const uint4*>(Yh + (size_t)s0 * D + sub * 8);
        uint4 u1 = *reinterpret_cast<const uint4*>(Yh + (size_t)s1 * D + sub * 8);
        addrow(acc, u0);
        addrow(acc, u1);
    }
    if (e + 8 <= cnt) {
        int s0 = srt[start + e + g];
        uint4 u0 = *reinterpret_cast<const uint4*>(Yh + (size_t)s0 * D + sub * 8);
        addrow(acc, u0);
        e += 8;
    }
    if (e + g < cnt) {
        int s0 = srt[start + e + g];
        uint4 u0 = *reinterpret_cast<const uint4*>(Yh + (size_t)s0 * D + sub * 8);
        addrow(acc, u0);
    }

    #pragma unroll
    for (int j = 0; j < 8; ++j) {
        acc[j] += __shfl_xor(acc[j], 8, 64);
        acc[j] += __shfl_xor(acc[j], 16, 64);
        acc[j] += __shfl_xor(acc[j], 32, 64);
    }

    if (g == 0) {
        const float sc = rsqrtf((float)cnt + 1.0f);
        const float4 b0 = *reinterpret_cast<const float4*>(bias + sub * 8);
        const float4 b1 = *reinterpret_cast<const float4*>(bias + sub * 8 + 4);
        float4 r0, r1;
        r0.x = acc[0] * sc + b0.x;  r0.y = acc[1] * sc + b0.y;
        r0.z = acc[2] * sc + b0.z;  r0.w = acc[3] * sc + b0.w;
        r1.x = acc[4] * sc + b1.x;  r1.y = acc[5] * sc + b1.y;
        r1.z = acc[6] * sc + b1.z;  r1.w = acc[7] * sc + b1.w;
        *reinterpret_cast<float4*>(out + (size_t)node * D + sub * 8)     = r0;
        *reinterpret_cast<float4*>(out + (size_t)node * D + sub * 8 + 4) = r1;
    }
}

// ---------------------------------------------------------------------------
// mid tier: round-0 proven pipeline (fp32 throughout)
// ---------------------------------------------------------------------------

__global__ __launch_bounds__(256) void linear_kernel(
    const float* __restrict__ vertices,
    const float* __restrict__ weight,
    float* __restrict__ Y)
{
    __shared__ float rowbuf[4][64];
    const int wid  = threadIdx.x >> 6;
    const int lane = threadIdx.x & 63;
    float w[64];
    #pragma unroll
    for (int f = 0; f < 64; ++f) w[f] = weight[lane * 64 + f];
    const int nodesPerIter = gridDim.x * 4;
    for (int base = blockIdx.x * 4; base < N_NODES; base += nodesPerIter) {
        const int node = base + wid;
        float a = 0.0f;
        if (node < N_NODES) a = vertices[(size_t)node * D + lane];
        rowbuf[wid][lane] = a;
        __syncthreads();
        float acc = 0.0f;
        #pragma unroll
        for (int f = 0; f < 64; ++f)
            acc += rowbuf[wid][f] * w[f];
        if (node < N_NODES) Y[(size_t)node * D + lane] = acc;
        __syncthreads();
    }
}

__global__ __launch_bounds__(256) void gather_f32(
    const float* __restrict__ Y,
    const int* __restrict__ offsets,
    const int* __restrict__ deg,
    const int* __restrict__ sortedSrc,
    const float* __restrict__ bias,
    float* __restrict__ out)
{
    const int wid  = threadIdx.x >> 6;
    const int lane = threadIdx.x & 63;
    const int g    = lane >> 4;
    const int sub  = lane & 15;
    const int node = blockIdx.x * 4 + wid;
    if (node >= N_NODES) return;

    const int start = offsets[node];
    const int cnt   = deg[node];

    float4 acc;
    if (g == 0) {
        acc = *reinterpret_cast<const float4*>(Y + (size_t)node * D + (sub << 2));
    } else {
        acc.x = 0.0f; acc.y = 0.0f; acc.z = 0.0f; acc.w = 0.0f;
    }

    int e = 0;
    for (; e + 8 <= cnt; e += 8) {
        int s0 = sortedSrc[start + e + g];
        int s1 = sortedSrc[start + e + 4 + g];
        const float4 a0 = *reinterpret_cast<const float4*>(Y + (size_t)s0 * D + (sub << 2));
        const float4 a1 = *reinterpret_cast<const float4*>(Y + (size_t)s1 * D + (sub << 2));
        acc.x += a0.x; acc.y += a0.y; acc.z += a0.z; acc.w += a0.w;
        acc.x += a1.x; acc.y += a1.y; acc.z += a1.z; acc.w += a1.w;
    }
    if (e + 4 <= cnt) {
        int s0 = sortedSrc[start + e + g];
        const float4 a0 = *reinterpret_cast<const float4*>(Y + (size_t)s0 * D + (sub << 2));
        acc.x += a0.x; acc.y += a0.y; acc.z += a0.z; acc.w += a0.w;
        e += 4;
    }
    if (e + g < cnt) {
        int s0 = sortedSrc[start + e + g];
        const float4 a0 = *reinterpret_cast<const float4*>(Y + (size_t)s0 * D + (sub << 2));
        acc.x += a0.x; acc.y += a0.y; acc.z += a0.z; acc.w += a0.w;
    }

    acc.x += __shfl_xor(acc.x, 16, 64);
    acc.y += __shfl_xor(acc.y, 16, 64);
    acc.z += __shfl_xor(acc.z, 16, 64);
    acc.w += __shfl_xor(acc.w, 16, 64);
    acc.x += __shfl_xor(acc.x, 32, 64);
    acc.y += __shfl_xor(acc.y, 32, 64);
    acc.z += __shfl_xor(acc.z, 32, 64);
    acc.w += __shfl_xor(acc.w, 32, 64);

    if (lane < 16) {
        const float sc = rsqrtf((float)cnt + 1.0f);
        const float4 b4 = *reinterpret_cast<const float4*>(bias + (sub << 2));
        float4 r;
        r.x = acc.x * sc + b4.x;
        r.y = acc.y * sc + b4.y;
        r.z = acc.z * sc + b4.z;
        r.w = acc.w * sc + b4.w;
        *reinterpret_cast<float4*>(out + (size_t)node * D + (sub << 2)) = r;
    }
}

__global__ __launch_bounds__(256) void hist_kernel(const int* __restrict__ edges,
                                                   int* __restrict__ deg)
{
    int e = blockIdx.x * 256 + threadIdx.x;
    if (e < N_EDGES) atomicAdd(&deg[edges[e]], 1);
}

__global__ __launch_bounds__(256) void scan_part(const int* __restrict__ deg,
                                                 int* __restrict__ partial)
{
    int t = threadIdx.x;
    int base = blockIdx.x * SCAN_CHUNK + t * 4;
    int s = 0;
    #pragma unroll
    for (int k = 0; k < 4; ++k) { int i = base + k; if (i < N_NODES) s += deg[i]; }
    int lane = t & 63, wid = t >> 6;
    #pragma unroll
    for (int off = 32; off; off >>= 1) s += __shfl_down(s, off, 64);
    __shared__ int red[4];
    if (lane == 0) red[wid] = s;
    __syncthreads();
    if (t == 0) partial[blockIdx.x] = red[0] + red[1] + red[2] + red[3];
}

__global__ void scan_small(int* partial) {
    int lane = threadIdx.x;
    int v0 = (lane < NCHUNK) ? partial[lane] : 0;
    int v1 = (64 + lane < NCHUNK) ? partial[64 + lane] : 0;
    int i0 = waveInclScan(v0, lane);
    int tot0 = __shfl(i0, 63, 64);
    int i1 = waveInclScan(v1, lane) + tot0;
    if (lane < NCHUNK) partial[lane] = i0 - v0;
    if (64 + lane < NCHUNK) partial[64 + lane] = i1 - v1;
}

__global__ __launch_bounds__(256) void scan_final(const int* __restrict__ deg,
                                                  const int* __restrict__ partial,
                                                  int* __restrict__ offsets,
                                                  int* __restrict__ cursor)
{
    int t = threadIdx.x;
    int base = blockIdx.x * SCAN_CHUNK + t * 4;
    int d[4]; int s = 0;
    #pragma unroll
    for (int k = 0; k < 4; ++k) { int i = base + k; d[k] = (i < N_NODES) ? deg[i] : 0; s += d[k]; }
    __shared__ int sd[256];
    sd[t] = s; __syncthreads();
    #pragma unroll
    for (int off = 1; off < 256; off <<= 1) {
        int v = (t >= off) ? sd[t - off] : 0;
        __syncthreads();
        sd[t] += v;
        __syncthreads();
    }
    int excl = sd[t] - s + partial[blockIdx.x];
    #pragma unroll
    for (int k = 0; k < 4; ++k) {
        int i = base + k;
        if (i < N_NODES) { offsets[i] = excl; cursor[i] = excl; excl += d[k]; }
    }
}

__global__ __launch_bounds__(256) void scatter_idx(const int* __restrict__ edges,
                                                   int* __restrict__ cursor,
                                                   int* __restrict__ sortedSrc)
{
    int e = blockIdx.x * 256 + threadIdx.x;
    if (e >= N_EDGES) return;
    int dst = edges[e];
    int src = edges[N_EDGES + e];
    int pos = atomicAdd(&cursor[dst], 1);
    sortedSrc[pos] = src;
}

// ---------------------------------------------------------------------------
// last-resort fallback (round-1, proven)
// ---------------------------------------------------------------------------

__global__ __launch_bounds__(256) void fb_scatter(
    const float* __restrict__ vertices, const int* __restrict__ edges,
    float* __restrict__ agg, float* __restrict__ degF)
{
    long long tid = (long long)blockIdx.x * 256 + threadIdx.x;
    int lane = threadIdx.x & 63;
    long long e = tid >> 6;
    if (e >= N_EDGES) return;
    int dst = edges[e];
    int src = edges[N_EDGES + e];
    atomicAdd(&agg[(size_t)dst * D + lane], vertices[(size_t)src * D + lane]);
    if (lane == 0) atomicAdd(&degF[dst], 1.0f);
}

__global__ __launch_bounds__(256) void fb_finish(
    const float* __restrict__ vertices, const float* __restrict__ weight,
    const float* __restrict__ bias, const float* __restrict__ degF,
    float* __restrict__ out)
{
    __shared__ float rowbuf[4][64];
    const int wid  = threadIdx.x >> 6;
    const int lane = threadIdx.x & 63;
    float w[64];
    #pragma unroll
    for (int f = 0; f < 64; ++f) w[f] = weight[lane * 64 + f];
    const float b = bias[lane];
    const int nodesPerIter = gridDim.x * 4;
    for (int base = blockIdx.x * 4; base < N_NODES; base += nodesPerIter) {
        const int node = base + wid;
        float a = 0.0f;
        if (node < N_NODES) {
            const float scale = rsqrtf(degF[node] + 1.0f);
            a = (out[(size_t)node * D + lane] + vertices[(size_t)node * D + lane]) * scale;
        }
        rowbuf[wid][lane] = a;
        __syncthreads();
        float acc = b;
        #pragma unroll
        for (int f = 0; f < 64; ++f) acc += rowbuf[wid][f] * w[f];
        if (node < N_NODES) out[(size_t)node * D + lane] = acc;
        __syncthreads();
    }
}

extern "C" void kernel_launch(void* const* d_in, const int* in_sizes, int n_in,
                              void* d_out, int out_size, void* d_ws, size_t ws_size,
                              hipStream_t stream) {
    const float* vertices = (const float*)d_in[0];
    const int*   edges    = (const int*)d_in[1];
    const float* weight   = (const float*)d_in[2];
    const float* bias     = (const float*)d_in[3];
    float* out = (float*)d_out;

    const int threads = 256;
    const int edgeBlocks = (N_EDGES + threads - 1) / threads;

    // --- fast layout: Yh(fp16) | bcntC | cursorDelta | bbaseC | offs | deg | packed | srt
    {
        __half* Yh         = (__half*)d_ws;
        int*   bcntC       = (int*)(Yh + (size_t)N_NODES * D);
        int*   cursorDelta = bcntC + NBC;
        int*   bbaseC      = cursorDelta + NBC;
        int*   offs        = bbaseC + NBC;
        int*   deg         = offs + N_NODES;
        int*   packed      = deg + N_NODES;
        int*   srt         = packed + N_EDGES;
        size_t needed      = (size_t)((char*)(srt + N_EDGES) - (char*)d_ws);
        if (ws_size >= needed) {
            hipMemsetAsync(bcntC, 0, sizeof(int) * 2 * NBC, stream);  // bcntC + cursorDelta
            lin_hist<<<LINB + SPLITB, threads, 0, stream>>>(vertices, weight, Yh, edges, bcntC);
            s_scatter<<<NBLK2, 1024, 0, stream>>>(edges, bcntC, cursorDelta, bbaseC, packed);
            csr512<<<NBC, 1024, 0, stream>>>(packed, bbaseC, bcntC, offs, deg, srt);
            gather_h<<<(N_NODES + 3) / 4, threads, 0, stream>>>(Yh, offs, deg, srt, bias, out);
            return;
        }
    }

    // --- mid layout (round-0 proven): Y | deg | offsets | cursor | partial[128] | srt
    {
        float* Y       = (float*)d_ws;
        int*   deg     = (int*)(Y + (size_t)N_NODES * D);
        int*   offs    = deg + N_NODES;
        int*   cursor  = offs + N_NODES;
        int*   partial = cursor + N_NODES;
        int*   srt     = partial + 128;
        size_t needed  = (size_t)((char*)(srt + N_EDGES) - (char*)d_ws);
        if (ws_size >= needed) {
            hipMemsetAsync(deg, 0, sizeof(int) * N_NODES, stream);
            linear_kernel<<<1024, threads, 0, stream>>>(vertices, weight, Y);
            hist_kernel<<<edgeBlocks, threads, 0, stream>>>(edges, deg);
            scan_part<<<NCHUNK, threads, 0, stream>>>(deg, partial);
            scan_small<<<1, 64, 0, stream>>>(partial);
            scan_final<<<NCHUNK, threads, 0, stream>>>(deg, partial, offs, cursor);
            scatter_idx<<<edgeBlocks, threads, 0, stream>>>(edges, cursor, srt);
            gather_f32<<<(N_NODES + 3) / 4, threads, 0, stream>>>(Y, offs, deg, srt, bias, out);
            return;
        }
    }

    // --- last resort
    {
        float* degF = (float*)d_ws;
        hipMemsetAsync(out, 0, sizeof(float) * (size_t)N_NODES * D, stream);
        hipMemsetAsync(degF, 0, sizeof(float) * N_NODES, stream);
        const long long totalScatter = (long long)N_EDGES * 64;
        fb_scatter<<<(int)((totalScatter + threads - 1) / threads), threads, 0, stream>>>(
            vertices, edges, out, degF);
        fb_finish<<<1024, threads, 0, stream>>>(vertices, weight, bias, degF, out);
    }
}